// Round 6
// baseline (1149.286 us; speedup 1.0000x reference)
//
#include <hip/hip_runtime.h>
#include <hip/hip_bf16.h>

// Round 13: race fix for r12 (absmax drifted 0.03125 -> 0.105: wm=1 waves'
// RD_A at ph2/ph6 read A-h1 regions whose stages were only drained at the
// NEXT vmcnt -- uncovered in-flight global_load_lds). New coverage-correct
// schedule: per-tile stage order {Bh0,Bh1,Ah0,Ah1} at phases {1,2,2,3} and
// {5,6,6,7}; vmcnt(8) at ph3/ph7 drains whole tiles (consecutive in issue
// order); ahead-A reads moved AFTER the vmcnt+barrier (ph3/ph7 post) so the
// same-phase drain covers them. Ledger verified for both wm halves; stages
// issue >=1 barrier after the old region's last read; drains target loads
// 4-6 phases old (never exposed). Accumulation order unchanged -> absmax
// must return to 0.03125 (verification signal).
// f32 in/out per reference; bf16 MFMA internally. B=8, N=2048, DA=768, DB=1024.

#define AS1 __attribute__((address_space(1)))
#define AS3 __attribute__((address_space(3)))

typedef __attribute__((ext_vector_type(8))) short bf16x8;
typedef __attribute__((ext_vector_type(4))) float f32x4;

using bf = __hip_bfloat16;

// ---------------- unified 256x256 8-phase GEMM (BK=64, 2 tiles/iter) -------
// C = alpha * A[M,K] @ BT[Nc,K]^T.
// nseg==1: (+bias)(+resid32/resid16) -> C16 and/or C32, ldc=Nc, tstore bit0.
// nseg>1 : 1024-col segments -> {C16,C16b,C16c} w/ biases {bias,biasB,biasC};
//          tstore bit s stores segment s transposed per 2048-row batch.
// Constraints: M%256==0, Nc%256==0, K%128==0, gx*gy%8==0 (all sites satisfy).
__global__ __launch_bounds__(512, 1) void gemm256(
    const bf* __restrict__ A, const bf* __restrict__ BT,
    const float* __restrict__ bias, const float* __restrict__ biasB,
    const float* __restrict__ biasC,
    const float* __restrict__ resid32, const bf* __restrict__ resid16,
    bf* __restrict__ C16, bf* __restrict__ C16b, bf* __restrict__ C16c,
    float* __restrict__ C32,
    int M, int Nc, int K, float alpha,
    long sA, long sB, long sC, int tstore, int nseg)
{
    // [buf:2][mat:2][half:2][row:128][col:64] bf16 = 128 KiB.
    // mat 0 = A, 1 = B; half h = rows [h*128, h*128+128) of the 256-tile.
    __shared__ __align__(16) char lds[131072];

    const int tid  = threadIdx.x;
    const int wave = tid >> 6;        // 0..7
    const int lane = tid & 63;
    const int wm = wave >> 2;         // 0..1 : M half (128 rows)
    const int wn = wave & 3;          // 0..3 : N quarter (64 cols)

    // XCD-aware bijective swizzle (T1; valid since gx*gy%8==0).
    const int gx = gridDim.x, gy = gridDim.y;
    int wg = blockIdx.y * gx + blockIdx.x;
    const int nwg = gx * gy;
    if (!(nwg & 7)) wg = (wg & 7) * (nwg >> 3) + (wg >> 3);
    const int m0 = (wg / gx) * 256;
    const int n0 = (wg % gx) * 256;

    const long zC = (long)blockIdx.z * sC;
    A  += (long)blockIdx.z * sA;
    BT += (long)blockIdx.z * sB;

    const int fl = lane & 15, qd = lane >> 4;
    const long ldb = (long)K * 2;

    // Staging: half-tile = [128 rows][64 cols] = 16 KB; per wave 2 loads of
    // 8 rows (1 KB each): rows wave*8+(lane>>3) and 64+wave*8+(lane>>3).
    // LDS dest linear; source chunk pre-swizzled: LDS slot s of row R holds
    // global chunk s ^ (R&7); R&7 == lane>>3 for staging lanes.
    const int scn = (lane & 7) ^ (lane >> 3);
    const char* gA = (const char*)A  + (long)(m0 + (lane >> 3)) * ldb + scn * 16;
    const char* gB = (const char*)BT + (long)(n0 + (lane >> 3)) * ldb + scn * 16;

    auto stage = [&](int mat, int h, int t) {   // half-tile (mat,h) of K-tile t
        const char* g = (mat ? gB : gA) + (long)(h * 128 + wave * 8) * ldb + (long)t * 128;
        char* l = lds + (t & 1) * 65536 + mat * 32768 + h * 16384 + wave * 1024;
        __builtin_amdgcn_global_load_lds((const AS1 void*)g,            (AS3 void*)l,        16, 0, 0);
        __builtin_amdgcn_global_load_lds((const AS1 void*)(g + 64*ldb), (AS3 void*)(l + 8192), 16, 0, 0);
    };

    // Fragment reads: k-chunk c = h*4+qd of row R lives at slot c^(R&7);
    // R&7 == fl&7 for all fragment rows. 2-way bank aliasing only (free).
    const int s0slot = qd ^ (fl & 7);
    const int so0 = s0slot * 16;
    const int so1 = (s0slot ^ 4) * 16;
    const char* AbH0 = lds + wm * 16384 + fl * 128 + so0;
    const char* AbH1 = lds + wm * 16384 + fl * 128 + so1;
    const char* BbH0 = lds + 32768 + (wn >> 1) * 16384 + (wn & 1) * 8192 + fl * 128 + so0;
    const char* BbH1 = lds + 32768 + (wn >> 1) * 16384 + (wn & 1) * 8192 + fl * 128 + so1;

    f32x4 acc[8][4];
#pragma unroll
    for (int i = 0; i < 8; ++i)
#pragma unroll
        for (int j = 0; j < 4; ++j)
            acc[i][j] = (f32x4){0.f, 0.f, 0.f, 0.f};

    bf16x8 aA[4][2], aB[4][2];             // A quadrant sets [frag][khalf]
    bf16x8 bP[2][2], bQ1[2][2];            // B sets (nq0 / nq1)

#define RD_A(dst, SL, mq) { \
    const char* pa0_ = AbH0 + (SL) * 65536 + (mq) * 8192; \
    const char* pa1_ = AbH1 + (SL) * 65536 + (mq) * 8192; \
    _Pragma("unroll") for (int f_ = 0; f_ < 4; ++f_) { \
        dst[f_][0] = *(const bf16x8*)(pa0_ + f_ * 2048); \
        dst[f_][1] = *(const bf16x8*)(pa1_ + f_ * 2048); } }

#define RD_B(dst, SL, nq) { \
    const char* pb0_ = BbH0 + (SL) * 65536 + (nq) * 4096; \
    const char* pb1_ = BbH1 + (SL) * 65536 + (nq) * 4096; \
    _Pragma("unroll") for (int g_ = 0; g_ < 2; ++g_) { \
        dst[g_][0] = *(const bf16x8*)(pb0_ + g_ * 2048); \
        dst[g_][1] = *(const bf16x8*)(pb1_ + g_ * 2048); } }

#define MFMA_Q(AF, BF, mq, nq) { \
    __builtin_amdgcn_s_setprio(1); \
    _Pragma("unroll") for (int f_ = 0; f_ < 4; ++f_) \
    _Pragma("unroll") for (int g_ = 0; g_ < 2; ++g_) \
    _Pragma("unroll") for (int h_ = 0; h_ < 2; ++h_) \
        acc[(mq)*4+f_][(nq)*2+g_] = __builtin_amdgcn_mfma_f32_16x16x32_bf16( \
            AF[f_][h_], BF[g_][h_], acc[(mq)*4+f_][(nq)*2+g_], 0, 0, 0); \
    __builtin_amdgcn_s_setprio(0); }

#define BAR() __builtin_amdgcn_s_barrier()
#define VMC(N) asm volatile("s_waitcnt vmcnt(" #N ")" ::: "memory")

    const int NT    = K >> 6;     // K-tiles (even at all call sites)
    const int niter = NT >> 1;

    // Prologue: stage t0 {B0,B1,A0,A1}, t1 {B0,B1,A0,A1} (16 items/wave);
    // VMC(8) drains tile0's 8 -> tile0 landed, tile1 in flight (invariant).
#pragma unroll
    for (int t = 0; t < 2; ++t) {
        stage(1, 0, t); stage(1, 1, t); stage(0, 0, t); stage(0, 1, t);
    }
    VMC(8);
    BAR();
    RD_A(aA, 0, 0);                // tile0 A, quadrant mq0

    for (int I = 0; I < niter; ++I) {
        const int n0t = 2 * I + 2, n1t = 2 * I + 3;
        const bool sa = n0t < NT;  // false only in the last iteration
        // ---- K-tile 2I (slot 0) ----
        // ph0: read cur0-B (both sets); no stage (old B reads this phase)
        RD_B(bP, 0, 0); RD_B(bQ1, 0, 1);
        BAR(); MFMA_Q(aA, bP, 0, 0); BAR();
        // ph1: read cur0-A mq1; stage nxt0.Bh0 (old B reads were ph0)
        RD_A(aB, 0, 1);
        if (sa) stage(1, 0, n0t);
        BAR(); MFMA_Q(aA, bQ1, 0, 1); BAR();
        // ph2: stage nxt0.{Bh1, Ah0} (old A reads were ph1)
        if (sa) { stage(1, 1, n0t); stage(0, 0, n0t); }
        BAR(); MFMA_Q(aB, bQ1, 1, 1); BAR();
        // ph3: stage nxt0.Ah1; vmcnt(8) drains cur1 fully; post-read cur1-A mq0
        if (sa) { stage(0, 1, n0t); VMC(8); } else { VMC(0); }
        BAR();
        RD_A(aA, 1, 0);
        MFMA_Q(aB, bP, 1, 0); BAR();
        // ---- K-tile 2I+1 (slot 1) ----
        // ph4: read cur1-B (covered by ph3 drain); no stage
        RD_B(bP, 1, 0); RD_B(bQ1, 1, 1);
        BAR(); MFMA_Q(aA, bP, 0, 0); BAR();
        // ph5: read cur1-A mq1; stage nxt1.Bh0
        RD_A(aB, 1, 1);
        if (sa) stage(1, 0, n1t);
        BAR(); MFMA_Q(aA, bQ1, 0, 1); BAR();
        // ph6: stage nxt1.{Bh1, Ah0}
        if (sa) { stage(1, 1, n1t); stage(0, 0, n1t); }
        BAR(); MFMA_Q(aB, bQ1, 1, 1); BAR();
        // ph7: stage nxt1.Ah1; vmcnt(8) drains nxt0 fully; post-read nxt0-A mq0
        if (sa) {
            stage(0, 1, n1t); VMC(8); BAR();
            RD_A(aA, 0, 0);
        } else {
            BAR();
        }
        MFMA_Q(aB, bP, 1, 0); BAR();
    }

    // Epilogue: C/D layout col = lane&15, row = qd*4 + r (verified m89/m91).
    if (nseg == 1) {
        const long ldc = Nc;
#pragma unroll
        for (int i = 0; i < 8; ++i) {
#pragma unroll
            for (int j = 0; j < 4; ++j) {
#pragma unroll
                for (int r = 0; r < 4; ++r) {
                    const int row = m0 + wm * 128 + i * 16 + qd * 4 + r;
                    const int col = n0 + wn * 64 + j * 16 + fl;
                    float v = acc[i][j][r] * alpha;
                    if (bias) v += bias[col];
                    if (tstore & 1) {
                        const long idx = (long)(row >> 11) * ((long)Nc * 2048)
                                       + (long)col * 2048 + (row & 2047);
                        C16[idx] = __float2bfloat16(v);
                    } else {
                        const long idx = zC + (long)row * ldc + col;
                        if (resid32) v += resid32[idx];
                        if (resid16) v += __bfloat162float(resid16[idx]);
                        if (C16) C16[idx] = __float2bfloat16(v);
                        if (C32) C32[idx] = v;
                    }
                }
            }
        }
    } else {
        const int seg = n0 >> 10;
        bf* dst = (seg == 0) ? C16 : ((seg == 1) ? C16b : C16c);
        const float* bseg = (seg == 0) ? bias : ((seg == 1) ? biasB : biasC);
        const int trans = (tstore >> seg) & 1;
        const int cb = n0 & 1023;
#pragma unroll
        for (int i = 0; i < 8; ++i) {
#pragma unroll
            for (int j = 0; j < 4; ++j) {
#pragma unroll
                for (int r = 0; r < 4; ++r) {
                    const int row = m0 + wm * 128 + i * 16 + qd * 4 + r;
                    const int col = cb + wn * 64 + j * 16 + fl;
                    float v = acc[i][j][r] * alpha + bseg[col];
                    const long idx = trans
                        ? (long)(row >> 11) * (1024L * 2048) + (long)col * 2048 + (row & 2047)
                        : (long)row * 1024 + col;
                    dst[idx] = __float2bfloat16(v);
                }
            }
        }
    }
#undef RD_A
#undef RD_B
#undef MFMA_Q
#undef BAR
#undef VMC
}

// elementwise f32 -> bf16, n must be a multiple of 8
__global__ __launch_bounds__(256) void cast_f32_bf16(
    const float* __restrict__ in, bf* __restrict__ out, long n)
{
    long i = ((long)blockIdx.x * 256 + threadIdx.x) * 8;
    if (i >= n) return;
    float4 a = *(const float4*)(in + i);
    float4 b = *(const float4*)(in + i + 4);
    bf o[8] = {__float2bfloat16(a.x), __float2bfloat16(a.y),
               __float2bfloat16(a.z), __float2bfloat16(a.w),
               __float2bfloat16(b.x), __float2bfloat16(b.y),
               __float2bfloat16(b.z), __float2bfloat16(b.w)};
    *(bf16x8*)(out + i) = *(bf16x8*)o;
}

// W[R,C] f32 -> WT[C,R] bf16
__global__ __launch_bounds__(256) void transpose_f32_bf16(
    const float* __restrict__ in, bf* __restrict__ out, int R, int C)
{
    __shared__ bf t[32][33];
    const int c0 = blockIdx.x * 32, r0 = blockIdx.y * 32;
    const int tx = threadIdx.x, ty = threadIdx.y;
#pragma unroll
    for (int i = ty; i < 32; i += 8)
        t[i][tx] = __float2bfloat16(in[(long)(r0 + i) * C + c0 + tx]);
    __syncthreads();
#pragma unroll
    for (int i = ty; i < 32; i += 8)
        out[(long)(c0 + i) * R + r0 + tx] = t[tx][i];
}

// In-place row softmax over 2048 bf16 cols; one 256-thread block per row.
__global__ __launch_bounds__(256) void softmax_rows(bf* __restrict__ S)
{
    const long row = blockIdx.x;
    bf* p = S + row * 2048;
    const int tx = threadIdx.x;

    float v[8];
    float m = -3.0e38f;
#pragma unroll
    for (int i = 0; i < 8; i++) {
        v[i] = __bfloat162float(p[tx + 256 * i]);
        m = fmaxf(m, v[i]);
    }
    __shared__ float red[4];
#pragma unroll
    for (int o = 1; o < 64; o <<= 1) m = fmaxf(m, __shfl_xor(m, o, 64));
    if ((tx & 63) == 0) red[tx >> 6] = m;
    __syncthreads();
    m = fmaxf(fmaxf(red[0], red[1]), fmaxf(red[2], red[3]));

    float s = 0.f;
#pragma unroll
    for (int i = 0; i < 8; i++) { v[i] = __expf(v[i] - m); s += v[i]; }
#pragma unroll
    for (int o = 1; o < 64; o <<= 1) s += __shfl_xor(s, o, 64);
    __syncthreads();
    if ((tx & 63) == 0) red[tx >> 6] = s;
    __syncthreads();
    const float inv = 1.0f / (red[0] + red[1] + red[2] + red[3]);
#pragma unroll
    for (int i = 0; i < 8; i++) p[tx + 256 * i] = __float2bfloat16(v[i] * inv);
}

extern "C" void kernel_launch(void* const* d_in, const int* in_sizes, int n_in,
                              void* d_out, int out_size, void* d_ws, size_t ws_size,
                              hipStream_t stream)
{
    const int Bb = 8, Nn = 2048, DA = 768, DB = 1024;
    const long Mt = (long)Bb * Nn;   // 16384 tokens

    const float* x_a   = (const float*)d_in[0];
    const float* x_b   = (const float*)d_in[1];
    const float* sa_wq = (const float*)d_in[2];  const float* sa_bq = (const float*)d_in[3];
    const float* sa_wk = (const float*)d_in[4];  const float* sa_bk = (const float*)d_in[5];
    const float* sa_wv = (const float*)d_in[6];  const float* sa_bv = (const float*)d_in[7];
    const float* sa_wo = (const float*)d_in[8];  const float* sa_bo = (const float*)d_in[9];
    const float* ca_wq = (const float*)d_in[10]; const float* ca_bq = (const float*)d_in[11];
    const float* ca_wk = (const float*)d_in[12]; const float* ca_bk = (const float*)d_in[13];
    const float* ca_wv = (const float*)d_in[14]; const float* ca_bv = (const float*)d_in[15];
    const float* ca_wo = (const float*)d_in[16]; const float* ca_bo = (const float*)d_in[17];
    float* out = (float*)d_out;
    (void)in_sizes; (void)n_in; (void)out_size; (void)ws_size;

    // workspace carve-up (256B aligned): peak 207.5 MB (r3 layout proven)
    char* ws = (char*)d_ws;
    size_t off = 0;
    auto alloc = [&](size_t bytes) -> bf* {
        bf* p = (bf*)(ws + off);
        off += (bytes + 255) & ~(size_t)255;
        return p;
    };
    bf* wqkvT = alloc((size_t)3 * DB * DB * 2);  // [3072,1024] concat q,k,v
    bf* woT   = alloc((size_t)DB * DB * 2);
    bf* cwqT  = alloc((size_t)DB * DA * 2);      // [1024,768]
    bf* ckvT  = alloc((size_t)2 * DB * DB * 2);  // [2048,1024] concat k,v
    bf* cwoT  = alloc((size_t)DB * DB * 2);
    bf* slA   = alloc((size_t)Mt * DB * 2);      // xbB -> xaB -> VcT
    bf* slQ   = alloc((size_t)Mt * DB * 2);      // Q   -> Xb
    bf* slK   = alloc((size_t)Mt * DB * 2);      // K   -> attn -> Qc
    bf* slV   = alloc((size_t)Mt * DB * 2);      // VT  -> Kc
    bf* S     = alloc((size_t)Bb * Nn * Nn * 2);

    const dim3 tb(32, 8);
    const dim3 blk(256);
    const dim3 blk5(512);
    const long sQ = (long)Nn * DB;
    const long sS = (long)Nn * Nn;
    const float* nf = nullptr;
    const bf*    nb = nullptr;
    bf*          no = nullptr;

    // ---- ingestion: weight transposes (f32 -> bf16), concat layouts ----
    transpose_f32_bf16<<<dim3(DB/32, DB/32), tb, 0, stream>>>(sa_wq, wqkvT,                 DB, DB);
    transpose_f32_bf16<<<dim3(DB/32, DB/32), tb, 0, stream>>>(sa_wk, wqkvT + (size_t)DB*DB, DB, DB);
    transpose_f32_bf16<<<dim3(DB/32, DB/32), tb, 0, stream>>>(sa_wv, wqkvT + (size_t)2*DB*DB, DB, DB);
    transpose_f32_bf16<<<dim3(DB/32, DB/32), tb, 0, stream>>>(sa_wo, woT,  DB, DB);
    transpose_f32_bf16<<<dim3(DB/32, DA/32), tb, 0, stream>>>(ca_wq, cwqT, DA, DB);
    transpose_f32_bf16<<<dim3(DB/32, DB/32), tb, 0, stream>>>(ca_wk, ckvT,                 DB, DB);
    transpose_f32_bf16<<<dim3(DB/32, DB/32), tb, 0, stream>>>(ca_wv, ckvT + (size_t)DB*DB, DB, DB);
    transpose_f32_bf16<<<dim3(DB/32, DB/32), tb, 0, stream>>>(ca_wo, cwoT, DB, DB);

    // ---- self-attention ----
    cast_f32_bf16<<<dim3((unsigned)(Mt * DB / 8 / 256)), blk, 0, stream>>>(x_b, slA, Mt * DB);
    // fused QKV: Q->slQ, K->slK, V->slV (transposed per batch)
    gemm256<<<dim3(3*DB/256, Mt/256, 1), blk5, 0, stream>>>(
        slA, wqkvT, sa_bq, sa_bk, sa_bv, nf, nb, slQ, slK, slV, nullptr,
        (int)Mt, 3*DB, DB, 1.0f, 0, 0, 0, 0b100, 3);
    // scores = (Q @ K^T) / 32
    gemm256<<<dim3(Nn/256, Nn/256, Bb), blk5, 0, stream>>>(
        slQ, slK, nf, nf, nf, nf, nb, S, no, no, nullptr,
        Nn, Nn, DB, 0.03125f, sQ, sQ, sS, 0, 1);
    softmax_rows<<<dim3((unsigned)(Bb * Nn)), blk, 0, stream>>>(S);
    // attn = P @ V (VT as B^T) -> slK (K dead)
    gemm256<<<dim3(DB/256, Nn/256, Bb), blk5, 0, stream>>>(
        S, slV, nf, nf, nf, nf, nb, slK, no, no, nullptr,
        Nn, DB, Nn, 1.0f, sS, sQ, sQ, 0, 1);
    // x_b_new = x_b(f32) + attn @ Wo + bo -> slQ (Q dead)
    gemm256<<<dim3(DB/256, Mt/256, 1), blk5, 0, stream>>>(
        slK, woT, sa_bo, nf, nf, x_b, nb, slQ, no, no, nullptr,
        (int)Mt, DB, DB, 1.0f, 0, 0, 0, 0, 1);

    // ---- cross-attention ----
    cast_f32_bf16<<<dim3((unsigned)(Mt * DA / 8 / 256)), blk, 0, stream>>>(x_a, slA, Mt * DA);
    // Qc = xa @ cwq -> slK (attn dead)   [K=768 -> 12 K-tiles, 6 iters]
    gemm256<<<dim3(DB/256, Mt/256, 1), blk5, 0, stream>>>(
        slA, cwqT, ca_bq, nf, nf, nf, nb, slK, no, no, nullptr,
        (int)Mt, DB, DA, 1.0f, 0, 0, 0, 0, 1);
    // fused cKV from Xb(slQ): Kc->slV (VT dead), Vc->slA transposed (xaB dead)
    gemm256<<<dim3(2*DB/256, Mt/256, 1), blk5, 0, stream>>>(
        slQ, ckvT, ca_bk, ca_bv, nf, nf, nb, slV, slA, no, nullptr,
        (int)Mt, 2*DB, DB, 1.0f, 0, 0, 0, 0b10, 2);
    // scores = (Qc @ Kc^T) / sqrt(768)
    gemm256<<<dim3(Nn/256, Nn/256, Bb), blk5, 0, stream>>>(
        slK, slV, nf, nf, nf, nf, nb, S, no, no, nullptr,
        Nn, Nn, DB, 0.036084391824351615f, sQ, sQ, sS, 0, 1);
    softmax_rows<<<dim3((unsigned)(Bb * Nn)), blk, 0, stream>>>(S);
    // ca_attn = P @ Vc -> slV (Kc dead)
    gemm256<<<dim3(DB/256, Nn/256, Bb), blk5, 0, stream>>>(
        S, slA, nf, nf, nf, nf, nb, slV, no, no, nullptr,
        Nn, DB, Nn, 1.0f, sS, sQ, sQ, 0, 1);
    // out(f32) = x_b_new(bf16, slQ) + ca_attn @ Wo + bo
    gemm256<<<dim3(DB/256, Mt/256, 1), blk5, 0, stream>>>(
        slV, cwoT, ca_bo, nf, nf, nf, slQ, no, no, no, out,
        (int)Mt, DB, DB, 1.0f, 0, 0, 0, 0, 1);
}